// Round 8
// baseline (244.311 us; speedup 1.0000x reference)
//
#include <hip/hip_runtime.h>
#include <cstddef>
#include <cstdint>

#define SEQ    2048
#define NBATCH 2

typedef unsigned short u16;
typedef unsigned int   u32;
typedef __attribute__((ext_vector_type(8))) short bf16x8;  // 8 bf16 = 4 VGPRs
typedef __attribute__((ext_vector_type(4))) float f32x4;

#if __has_builtin(__builtin_amdgcn_exp2f)
#define EXP2F(x) __builtin_amdgcn_exp2f(x)
#else
#define EXP2F(x) exp2f(x)
#endif

__device__ __forceinline__ u32 fbits(float x) { union { float f; u32 u; } c; c.f = x; return c.u; }
__device__ __forceinline__ u16 f2bf(float x) { return (u16)((fbits(x) + 0x8000u) >> 16); }
// pack two floats -> (bf16(hi)<<16) | bf16(lo)
__device__ __forceinline__ u32 pack2bf(float lo, float hi) {
    return __builtin_amdgcn_perm(fbits(hi) + 0x8000u, fbits(lo) + 0x8000u, 0x07060302u);
}

// ---------------------------------------------------------------------------
// one cast launch for all 7 tensors. grid (4096, 4)
// ---------------------------------------------------------------------------
__global__ __launch_bounds__(256)
void cast_all(const float* __restrict__ q, const float* __restrict__ k, const float* __restrict__ v,
              const float* __restrict__ wq, const float* __restrict__ wk,
              const float* __restrict__ wv, const float* __restrict__ wo,
              u16* __restrict__ oq, u16* __restrict__ ok, u16* __restrict__ ov,
              u16* __restrict__ owq, u16* __restrict__ owk, u16* __restrict__ owv,
              u16* __restrict__ owo)
{
    const float* s; u16* d; int i;
    if (blockIdx.y == 0)      { s = q; d = oq; i = blockIdx.x * 256 + threadIdx.x; }
    else if (blockIdx.y == 1) { s = k; d = ok; i = blockIdx.x * 256 + threadIdx.x; }
    else if (blockIdx.y == 2) { s = v; d = ov; i = blockIdx.x * 256 + threadIdx.x; }
    else {
        const int w = blockIdx.x >> 10, xi = blockIdx.x & 1023;
        if (w == 0)      { s = wq; d = owq; }
        else if (w == 1) { s = wk; d = owk; }
        else if (w == 2) { s = wv; d = owv; }
        else             { s = wo; d = owo; }
        i = xi * 256 + threadIdx.x;
    }
    float4 vv = ((const float4*)s)[i];
    uint2 r; r.x = pack2bf(vv.x, vv.y); r.y = pack2bf(vv.z, vv.w);
    ((uint2*)d)[i] = r;
}

// ---------------------------------------------------------------------------
// QKV GEMM body (proven): Y = X @ W^T, 128x128 tile, BK=64, reg-prefetch.
// layout 0: Y bf16 plain [m][1024]
// layout 2: Y bf16 transposed-through-LDS to [n,h,d,l]
// ---------------------------------------------------------------------------
__device__ __forceinline__
void gemm_body(const u16* __restrict__ X, const u16* __restrict__ W,
               void* __restrict__ Yv, const int layout)
{
    __shared__ u16 smem[2 * 128 * 72];
    u16* As = smem;
    u16* Bs = smem + 128 * 72;

    const int tid  = threadIdx.x;
    const int wave = tid >> 6;
    const int lane = tid & 63;
    const int lm   = lane & 15;
    const int quad = lane >> 4;
    const int m0 = blockIdx.x * 128;
    const int n0 = blockIdx.y * 128;
    const int wr = (wave & 1) * 64;
    const int wc = (wave >> 1) * 64;

    const int srow = tid >> 1;
    const int scol = (tid & 1) * 32;
    const u16* xg = X + (size_t)(m0 + srow) * 1024 + scol;
    const u16* wg = W + (size_t)(n0 + srow) * 1024 + scol;

    bf16x8 pa[4], pb[4];
    #pragma unroll
    for (int p = 0; p < 4; ++p) {
        pa[p] = *(const bf16x8*)(xg + p * 8);
        pb[p] = *(const bf16x8*)(wg + p * 8);
    }

    f32x4 acc[4][4] = {};

    for (int k0 = 0; k0 < 1024; k0 += 64) {
        __syncthreads();
        #pragma unroll
        for (int p = 0; p < 4; ++p) {
            *(bf16x8*)&As[srow * 72 + scol + p * 8] = pa[p];
            *(bf16x8*)&Bs[srow * 72 + scol + p * 8] = pb[p];
        }
        __syncthreads();
        if (k0 + 64 < 1024) {
            #pragma unroll
            for (int p = 0; p < 4; ++p) {
                pa[p] = *(const bf16x8*)(xg + k0 + 64 + p * 8);
                pb[p] = *(const bf16x8*)(wg + k0 + 64 + p * 8);
            }
        }
        #pragma unroll
        for (int kk = 0; kk < 64; kk += 32) {
            bf16x8 af[4], bf[4];
            #pragma unroll
            for (int t = 0; t < 4; ++t) {
                af[t] = *(const bf16x8*)&As[(wr + t * 16 + lm) * 72 + kk + quad * 8];
                bf[t] = *(const bf16x8*)&Bs[(wc + t * 16 + lm) * 72 + kk + quad * 8];
            }
            #pragma unroll
            for (int i = 0; i < 4; ++i)
                #pragma unroll
                for (int j = 0; j < 4; ++j)
                    acc[i][j] = __builtin_amdgcn_mfma_f32_16x16x32_bf16(af[i], bf[j], acc[i][j], 0, 0, 0);
        }
    }

    if (layout == 0) {
        u16* Y = (u16*)Yv;
        #pragma unroll
        for (int i = 0; i < 4; ++i)
            #pragma unroll
            for (int j = 0; j < 4; ++j) {
                const int C = n0 + wc + j * 16 + lm;
                #pragma unroll
                for (int r = 0; r < 4; ++r) {
                    const int R = m0 + wr + i * 16 + quad * 4 + r;
                    Y[(size_t)R * 1024 + C] = f2bf(acc[i][j][r]);
                }
            }
    } else {
        // transpose 128x128 C-tile through LDS, store [n,h,d,l]
        __syncthreads();
        u16* T = smem;              // [d_local][l_local], stride 132
        #pragma unroll
        for (int i = 0; i < 4; ++i)
            #pragma unroll
            for (int j = 0; j < 4; ++j) {
                const int col = wc + j * 16 + lm;
                const int row = wr + i * 16 + quad * 4;
                uint2 v;
                v.x = pack2bf(acc[i][j][0], acc[i][j][1]);
                v.y = pack2bf(acc[i][j][2], acc[i][j][3]);
                *(uint2*)&T[col * 132 + row] = v;
            }
        __syncthreads();
        const int dp = tid >> 1, half = (tid & 1) * 64;
        const int nn = m0 >> 11, l0 = m0 & 2047;
        const int C = n0 + dp, h = C >> 6, d = C & 63;
        u16* Y = (u16*)Yv;
        const size_t base = (((size_t)nn * 16 + h) * 64 + d) * SEQ + l0 + half;
        #pragma unroll
        for (int p = 0; p < 8; ++p) {
            bf16x8 v = *(const bf16x8*)&T[dp * 132 + half + p * 8];
            *(bf16x8*)(Y + base + p * 8) = v;
        }
    }
}

__global__ __launch_bounds__(256, 3)
void gemm_qkv(const u16* __restrict__ xq, const u16* __restrict__ xk, const u16* __restrict__ xv,
              const u16* __restrict__ wq, const u16* __restrict__ wk, const u16* __restrict__ wv,
              u16* __restrict__ qb, u16* __restrict__ kb, u16* __restrict__ vt)
{
    if (blockIdx.z == 0)      gemm_body(xq, wq, qb, 0);
    else if (blockIdx.z == 1) gemm_body(xk, wk, kb, 0);
    else                      gemm_body(xv, wv, vt, 2);
}

// ---------------------------------------------------------------------------
// Output GEMM: 128x64 tiles -> 512 blocks (2/CU). Y fp32 [m][1024] + bias.
// ---------------------------------------------------------------------------
__global__ __launch_bounds__(256, 2)
void gemm_out64(const u16* __restrict__ X, const u16* __restrict__ W,
                float* __restrict__ Y, const float* __restrict__ bias)
{
    __shared__ u16 As[128 * 72];
    __shared__ u16 Bs[64 * 72];

    const int tid  = threadIdx.x;
    const int wave = tid >> 6;
    const int lane = tid & 63;
    const int lm   = lane & 15;
    const int quad = lane >> 4;
    const int m0 = blockIdx.x * 128;
    const int n0 = blockIdx.y * 64;
    const int wr = (wave & 1) * 64;
    const int wc = (wave >> 1) * 32;

    const int arow = tid >> 1, acol = (tid & 1) * 32;
    const int brow = tid >> 2, bcol = (tid & 3) * 16;
    const u16* xg = X + (size_t)(m0 + arow) * 1024 + acol;
    const u16* wg = W + (size_t)(n0 + brow) * 1024 + bcol;

    bf16x8 pa[4], pb[2];
    #pragma unroll
    for (int p = 0; p < 4; ++p) pa[p] = *(const bf16x8*)(xg + p * 8);
    #pragma unroll
    for (int p = 0; p < 2; ++p) pb[p] = *(const bf16x8*)(wg + p * 8);

    f32x4 acc[4][2] = {};

    for (int k0 = 0; k0 < 1024; k0 += 64) {
        __syncthreads();
        #pragma unroll
        for (int p = 0; p < 4; ++p) *(bf16x8*)&As[arow * 72 + acol + p * 8] = pa[p];
        #pragma unroll
        for (int p = 0; p < 2; ++p) *(bf16x8*)&Bs[brow * 72 + bcol + p * 8] = pb[p];
        __syncthreads();
        if (k0 + 64 < 1024) {
            #pragma unroll
            for (int p = 0; p < 4; ++p) pa[p] = *(const bf16x8*)(xg + k0 + 64 + p * 8);
            #pragma unroll
            for (int p = 0; p < 2; ++p) pb[p] = *(const bf16x8*)(wg + k0 + 64 + p * 8);
        }
        #pragma unroll
        for (int kk = 0; kk < 64; kk += 32) {
            bf16x8 af[4], bf[2];
            #pragma unroll
            for (int t = 0; t < 4; ++t)
                af[t] = *(const bf16x8*)&As[(wr + t * 16 + lm) * 72 + kk + quad * 8];
            #pragma unroll
            for (int j = 0; j < 2; ++j)
                bf[j] = *(const bf16x8*)&Bs[(wc + j * 16 + lm) * 72 + kk + quad * 8];
            #pragma unroll
            for (int i = 0; i < 4; ++i)
                #pragma unroll
                for (int j = 0; j < 2; ++j)
                    acc[i][j] = __builtin_amdgcn_mfma_f32_16x16x32_bf16(af[i], bf[j], acc[i][j], 0, 0, 0);
        }
    }

    #pragma unroll
    for (int i = 0; i < 4; ++i)
        #pragma unroll
        for (int j = 0; j < 2; ++j) {
            const int C = n0 + wc + j * 16 + lm;
            const float bv = bias[C];
            #pragma unroll
            for (int r = 0; r < 4; ++r) {
                const int R = m0 + wr + i * 16 + quad * 4 + r;
                Y[(size_t)R * 1024 + C] = acc[i][j][r] + bv;
            }
        }
}

// ---------------------------------------------------------------------------
// Flash attention, 2-way KEY-SPLIT (grid 1024 = 4 blocks/CU for phase
// overlap of exp/LDS/MFMA pipes). Max-free softmax; 64-key chunks; Ps is a
// 32-key sliding window (wave-private, in-wave ds ordering makes reuse safe).
// Unnormalized O and l accumulated via fp32 atomicAdd into O32/Lb (zeroed by
// memset); combine_norm normalizes.  LDS 28.7 KB, VGPR<=128.
// ---------------------------------------------------------------------------
__global__ __launch_bounds__(256, 4)
void flash_attn_bf16(const u16* __restrict__ Qb, const u16* __restrict__ Kb,
                     const u16* __restrict__ VT, const int* __restrict__ mask,
                     float* __restrict__ O32, float* __restrict__ Lb)
{
    __shared__ u16 Ks[64 * 72];       // [key l][d]      9216 B
    __shared__ u16 Vts[64 * 72];      // [d][key l]      9216 B
    __shared__ u16 Ps[4][32 * 40];    // per-wave P [q][32-key window] 10240 B

    const int tid  = threadIdx.x;
    const int wave = tid >> 6;
    const int lane = tid & 63;
    const int lm   = lane & 15;
    const int quad = lane >> 4;

    // XCD-locality decode: all 32 blocks of one (n,h) share wid&7 -> one XCD
    const int wid  = blockIdx.x;            // 0..1023
    const int r_   = wid >> 3;              // 0..127
    const int hn   = (wid & 7) + 8 * (r_ & 3);
    const int h    = hn & 15, n = hn >> 4;
    const int qblk = (r_ >> 2) & 15;
    const int half = r_ >> 6;               // key half 0/1
    const int wq   = qblk * 128 + wave * 32;
    const int kbeg = half << 10;            // 0 or 1024

    const u16* Qh = Qb + ((size_t)n * SEQ) * 1024 + h * 64;
    const u16* Kh = Kb + ((size_t)n * SEQ) * 1024 + h * 64;
    const u16* Vh = VT + (((size_t)n * 16 + h) * 64) * SEQ;
    const int* mk = mask + (size_t)n * SEQ;
    u16* Pw = &Ps[wave][0];

    // Q fragments resident: A-layout m=lm, k=quad*8+j
    bf16x8 qf[2][2];
    #pragma unroll
    for (int t = 0; t < 2; ++t)
        #pragma unroll
        for (int s = 0; s < 2; ++s)
            qf[t][s] = *(const bf16x8*)(Qh + (size_t)(wq + t * 16 + lm) * 1024 + s * 32 + quad * 8);

    f32x4 o_acc[2][4] = {};
    float l_i[2][4] = {};

    // staging: K 64 keys x 64 d (4 thr/row); V 64 d x 64 keys (4 thr/row)
    const int kr = tid >> 2, kc = (tid & 3) * 16;

    bf16x8 ka[2], va[2];
    #pragma unroll
    for (int p = 0; p < 2; ++p) {
        ka[p] = *(const bf16x8*)(Kh + (size_t)(kbeg + kr) * 1024 + kc + p * 8);
        va[p] = *(const bf16x8*)(Vh + (size_t)kr * SEQ + kbeg + kc + p * 8);
    }

    const float cs = 0.125f * 1.44269504f;   // 1/sqrt(64) folded with log2(e)

    for (int c0 = kbeg; c0 < kbeg + 1024; c0 += 64) {
        __syncthreads();   // prior chunk's Ks/Vts reads complete
        #pragma unroll
        for (int p = 0; p < 2; ++p) {
            *(bf16x8*)&Ks[kr * 72 + kc + p * 8]  = ka[p];
            *(bf16x8*)&Vts[kr * 72 + kc + p * 8] = va[p];
        }
        __syncthreads();

        if (c0 + 64 < kbeg + 1024) {   // prefetch next chunk under compute
            #pragma unroll
            for (int p = 0; p < 2; ++p) {
                ka[p] = *(const bf16x8*)(Kh + (size_t)(c0 + 64 + kr) * 1024 + kc + p * 8);
                va[p] = *(const bf16x8*)(Vh + (size_t)kr * SEQ + c0 + 64 + kc + p * 8);
            }
        }

        // ---- S = Q K^T over 64 keys (4 n-tiles, 16 MFMAs)
        f32x4 s[2][4] = {};
        #pragma unroll
        for (int nt = 0; nt < 4; ++nt) {
            bf16x8 kf0 = *(const bf16x8*)&Ks[(nt * 16 + lm) * 72 + quad * 8];
            bf16x8 kf1 = *(const bf16x8*)&Ks[(nt * 16 + lm) * 72 + 32 + quad * 8];
            #pragma unroll
            for (int t = 0; t < 2; ++t) {
                s[t][nt] = __builtin_amdgcn_mfma_f32_16x16x32_bf16(qf[t][0], kf0, s[t][nt], 0, 0, 0);
                s[t][nt] = __builtin_amdgcn_mfma_f32_16x16x32_bf16(qf[t][1], kf1, s[t][nt], 0, 0, 0);
            }
        }

        // ---- exp2(scale*s), mask, row-sum accumulation (max-free)
        int msk[4];
        #pragma unroll
        for (int nt = 0; nt < 4; ++nt) msk[nt] = mk[c0 + nt * 16 + lm];
        #pragma unroll
        for (int t = 0; t < 2; ++t)
            #pragma unroll
            for (int nt = 0; nt < 4; ++nt)
                #pragma unroll
                for (int r = 0; r < 4; ++r) {
                    float e = EXP2F(s[t][nt][r] * cs);
                    e = msk[nt] ? e : 0.0f;
                    s[t][nt][r] = e;
                    l_i[t][r] += e;
                }

        // ---- two 32-key sub-steps: P -> wave-private window, then PV
        #pragma unroll
        for (int sb = 0; sb < 2; ++sb) {
            #pragma unroll
            for (int t = 0; t < 2; ++t)
                #pragma unroll
                for (int ntl = 0; ntl < 2; ++ntl)
                    #pragma unroll
                    for (int r = 0; r < 4; ++r)
                        Pw[(t * 16 + quad * 4 + r) * 40 + ntl * 16 + lm] =
                            f2bf(s[t][sb * 2 + ntl][r]);

            bf16x8 pf[2];
            #pragma unroll
            for (int t = 0; t < 2; ++t)
                pf[t] = *(const bf16x8*)&Pw[(t * 16 + lm) * 40 + quad * 8];
            #pragma unroll
            for (int dt = 0; dt < 4; ++dt) {
                bf16x8 vf = *(const bf16x8*)&Vts[(dt * 16 + lm) * 72 + sb * 32 + quad * 8];
                #pragma unroll
                for (int t = 0; t < 2; ++t)
                    o_acc[t][dt] = __builtin_amdgcn_mfma_f32_16x16x32_bf16(pf[t], vf, o_acc[t][dt], 0, 0, 0);
            }
        }
    }

    // ---- epilogue: atomic-accumulate unnormalized O and l
    #pragma unroll
    for (int t = 0; t < 2; ++t)
        #pragma unroll
        for (int r = 0; r < 4; ++r) {
            float v = l_i[t][r];
            #pragma unroll
            for (int off = 1; off < 16; off <<= 1) v += __shfl_xor(v, off);
            l_i[t][r] = v;   // all 16 lm lanes hold the row total
        }
    if (lm == 0) {
        #pragma unroll
        for (int t = 0; t < 2; ++t)
            #pragma unroll
            for (int r = 0; r < 4; ++r) {
                const int ql = wq + t * 16 + quad * 4 + r;
                atomicAdd(&Lb[(((size_t)n * 16 + h) << 11) + ql], l_i[t][r]);
            }
    }
    #pragma unroll
    for (int t = 0; t < 2; ++t)
        #pragma unroll
        for (int dt = 0; dt < 4; ++dt)
            #pragma unroll
            for (int r = 0; r < 4; ++r) {
                const int ql = wq + t * 16 + quad * 4 + r;
                const int col = h * 64 + dt * 16 + lm;
                atomicAdd(&O32[(((size_t)n * SEQ + ql) << 10) + col], o_acc[t][dt][r]);
            }
}

// ---------------------------------------------------------------------------
// normalize: attnb = bf16(O32 / l)
// ---------------------------------------------------------------------------
__global__ __launch_bounds__(256)
void combine_norm(const float* __restrict__ O32, const float* __restrict__ Lb,
                  u16* __restrict__ attnb)
{
    const int i = blockIdx.x * 256 + threadIdx.x;   // float4 idx, 1048576 total
    float4 o = ((const float4*)O32)[i];
    const int e4 = i & 255;
    const int h  = e4 >> 4;
    const int l  = (i >> 8) & 2047;
    const int n  = i >> 19;
    const float inv = 1.0f / Lb[(((size_t)n * 16 + h) << 11) + l];
    uint2 r; r.x = pack2bf(o.x * inv, o.y * inv); r.y = pack2bf(o.z * inv, o.w * inv);
    ((uint2*)attnb)[i] = r;
}

// ---------------------------------------------------------------------------
extern "C" void kernel_launch(void* const* d_in, const int* in_sizes, int n_in,
                              void* d_out, int out_size, void* d_ws, size_t ws_size,
                              hipStream_t stream)
{
    const float* values = (const float*)d_in[0];
    const float* keys   = (const float*)d_in[1];
    const float* query  = (const float*)d_in[2];
    const int*   mask   = (const int*)d_in[3];
    const float* W_q    = (const float*)d_in[4];
    const float* W_k    = (const float*)d_in[5];
    const float* W_v    = (const float*)d_in[6];
    const float* W_o    = (const float*)d_in[7];
    const float* b_o    = (const float*)d_in[8];

    const size_t NTOK = (size_t)NBATCH * SEQ * 1024;  // 4194304
    const size_t WSZ  = 1024 * 1024;
    u16* p = (u16*)d_ws;
    u16* qb    = p; p += NTOK;   // q  [n,l,e] bf16
    u16* kb    = p; p += NTOK;   // k  [n,l,e] bf16
    u16* vt    = p; p += NTOK;   // v^T[n,h,d,l] bf16
    u16* xq    = p; p += NTOK;   // bf16 input casts (dead after qkv)
    u16* xk    = p; p += NTOK;
    u16* xv    = p; p += NTOK;
    u16* attnb = p; p += NTOK;   // attn out [n,l,e] bf16
    u16* wqb   = p; p += WSZ;    // bf16 weight casts
    u16* wkb   = p; p += WSZ;
    u16* wvb   = p; p += WSZ;
    u16* wob   = p; p += WSZ;
    // flash partial accumulators alias the dead cast buffers:
    float* O32 = (float*)xq;     // [n,l,1024] fp32 = 16.78 MB (xq+xk)
    float* Lb  = (float*)xv;     // [n,h,2048] fp32 = 0.26 MB

    cast_all<<<dim3(4096, 4), 256, 0, stream>>>(query, keys, values,
                                                W_q, W_k, W_v, W_o,
                                                xq, xk, xv, wqb, wkb, wvb, wob);

    gemm_qkv<<<dim3(32, 8, 3), 256, 0, stream>>>(xq, xk, xv, wqb, wkb, wvb, qb, kb, vt);

    // zero O32 + Lb (contiguous: xq..xv region start)
    hipMemsetAsync(O32, 0, NTOK * 4 + 65536 * 4, stream);

    flash_attn_bf16<<<1024, 256, 0, stream>>>(qb, kb, vt, mask, O32, Lb);

    combine_norm<<<4096, 256, 0, stream>>>(O32, Lb, attnb);

    gemm_out64<<<dim3(32, 16), 256, 0, stream>>>(attnb, wob, (float*)d_out, b_o);
}

// Round 9
// 229.678 us; speedup vs baseline: 1.0637x; 1.0637x over previous
//
#include <hip/hip_runtime.h>
#include <cstddef>
#include <cstdint>

#define SEQ    2048
#define NBATCH 2

typedef unsigned short u16;
typedef unsigned int   u32;
typedef __attribute__((ext_vector_type(8))) short bf16x8;  // 8 bf16 = 4 VGPRs
typedef __attribute__((ext_vector_type(4))) float f32x4;

#if __has_builtin(__builtin_amdgcn_exp2f)
#define EXP2F(x) __builtin_amdgcn_exp2f(x)
#else
#define EXP2F(x) exp2f(x)
#endif

#define GLL16(g, l) __builtin_amdgcn_global_load_lds( \
    (const __attribute__((address_space(1))) void*)(g), \
    (__attribute__((address_space(3))) void*)(l), 16, 0, 0)

__device__ __forceinline__ u32 fbits(float x) { union { float f; u32 u; } c; c.f = x; return c.u; }
__device__ __forceinline__ u16 f2bf(float x) { return (u16)((fbits(x) + 0x8000u) >> 16); }
// pack two floats -> (bf16(hi)<<16) | bf16(lo)
__device__ __forceinline__ u32 pack2bf(float lo, float hi) {
    return __builtin_amdgcn_perm(fbits(hi) + 0x8000u, fbits(lo) + 0x8000u, 0x07060302u);
}

// ---------------------------------------------------------------------------
// one cast launch for all 7 tensors. grid (4096, 4)
// ---------------------------------------------------------------------------
__global__ __launch_bounds__(256)
void cast_all(const float* __restrict__ q, const float* __restrict__ k, const float* __restrict__ v,
              const float* __restrict__ wq, const float* __restrict__ wk,
              const float* __restrict__ wv, const float* __restrict__ wo,
              u16* __restrict__ oq, u16* __restrict__ ok, u16* __restrict__ ov,
              u16* __restrict__ owq, u16* __restrict__ owk, u16* __restrict__ owv,
              u16* __restrict__ owo)
{
    const float* s; u16* d; int i;
    if (blockIdx.y == 0)      { s = q; d = oq; i = blockIdx.x * 256 + threadIdx.x; }
    else if (blockIdx.y == 1) { s = k; d = ok; i = blockIdx.x * 256 + threadIdx.x; }
    else if (blockIdx.y == 2) { s = v; d = ov; i = blockIdx.x * 256 + threadIdx.x; }
    else {
        const int w = blockIdx.x >> 10, xi = blockIdx.x & 1023;
        if (w == 0)      { s = wq; d = owq; }
        else if (w == 1) { s = wk; d = owk; }
        else if (w == 2) { s = wv; d = owv; }
        else             { s = wo; d = owo; }
        i = xi * 256 + threadIdx.x;
    }
    float4 vv = ((const float4*)s)[i];
    uint2 r; r.x = pack2bf(vv.x, vv.y); r.y = pack2bf(vv.z, vv.w);
    ((uint2*)d)[i] = r;
}

// ---------------------------------------------------------------------------
// QKV GEMM body, m97 structure: Y = X @ W^T, 128x128 tile, BK=64,
// global_load_lds width-16 staging into UNPADDED stride-64 LDS.
// layout 0: Y bf16 plain [m][1024]
// layout 2: Y bf16 transposed-through-LDS to [n,h,d,l]
// ---------------------------------------------------------------------------
__device__ __forceinline__
void gemm_body(const u16* __restrict__ X, const u16* __restrict__ W,
               void* __restrict__ Yv, const int layout)
{
    // As/Bs: 128x64 bf16 each (8192 elems); T (epilogue) overlays: 128x132
    __shared__ u16 smem[16896];   // 33,792 B
    u16* As = smem;
    u16* Bs = smem + 8192;

    const int tid  = threadIdx.x;
    const int wave = tid >> 6;
    const int lane = tid & 63;
    const int lm   = lane & 15;
    const int quad = lane >> 4;
    const int m0 = blockIdx.x * 128;
    const int n0 = blockIdx.y * 128;
    const int wr = (wave & 1) * 64;
    const int wc = (wave >> 1) * 64;

    // staging: wave w stages rows [w*32, w*32+32); each GLL = 8 rows x 64 k
    const int srow = wave * 32 + (lane >> 3);
    const int scol = (lane & 7) * 8;
    const u16* xg = X + (size_t)(m0 + srow) * 1024 + scol;
    const u16* wg = W + (size_t)(n0 + srow) * 1024 + scol;

    f32x4 acc[4][4] = {};

    for (int k0 = 0; k0 < 1024; k0 += 64) {
        __syncthreads();   // previous iter's frag reads done
        #pragma unroll
        for (int p = 0; p < 4; ++p) {
            GLL16(xg + k0 + p * 8 * 1024, &As[(wave * 32 + p * 8) * 64]);
            GLL16(wg + k0 + p * 8 * 1024, &Bs[(wave * 32 + p * 8) * 64]);
        }
        __syncthreads();   // barrier drains vmcnt -> staging visible
        #pragma unroll
        for (int kk = 0; kk < 64; kk += 32) {
            bf16x8 af[4], bf[4];
            #pragma unroll
            for (int t = 0; t < 4; ++t) {
                af[t] = *(const bf16x8*)&As[(wr + t * 16 + lm) * 64 + kk + quad * 8];
                bf[t] = *(const bf16x8*)&Bs[(wc + t * 16 + lm) * 64 + kk + quad * 8];
            }
            #pragma unroll
            for (int i = 0; i < 4; ++i)
                #pragma unroll
                for (int j = 0; j < 4; ++j)
                    acc[i][j] = __builtin_amdgcn_mfma_f32_16x16x32_bf16(af[i], bf[j], acc[i][j], 0, 0, 0);
        }
    }

    if (layout == 0) {
        u16* Y = (u16*)Yv;
        #pragma unroll
        for (int i = 0; i < 4; ++i)
            #pragma unroll
            for (int j = 0; j < 4; ++j) {
                const int C = n0 + wc + j * 16 + lm;
                #pragma unroll
                for (int r = 0; r < 4; ++r) {
                    const int R = m0 + wr + i * 16 + quad * 4 + r;
                    Y[(size_t)R * 1024 + C] = f2bf(acc[i][j][r]);
                }
            }
    } else {
        // transpose 128x128 C-tile through LDS, store [n,h,d,l]
        __syncthreads();            // all frag reads of As/Bs done
        u16* T = smem;              // [d_local][l_local], stride 132
        #pragma unroll
        for (int i = 0; i < 4; ++i)
            #pragma unroll
            for (int j = 0; j < 4; ++j) {
                const int col = wc + j * 16 + lm;
                const int row = wr + i * 16 + quad * 4;
                uint2 v;
                v.x = pack2bf(acc[i][j][0], acc[i][j][1]);
                v.y = pack2bf(acc[i][j][2], acc[i][j][3]);
                *(uint2*)&T[col * 132 + row] = v;
            }
        __syncthreads();
        const int dp = tid >> 1, half = (tid & 1) * 64;
        const int nn = m0 >> 11, l0 = m0 & 2047;
        const int C = n0 + dp, h = C >> 6, d = C & 63;
        u16* Y = (u16*)Yv;
        const size_t base = (((size_t)nn * 16 + h) * 64 + d) * SEQ + l0 + half;
        #pragma unroll
        for (int p = 0; p < 8; ++p) {
            bf16x8 v = *(const bf16x8*)&T[dp * 132 + half + p * 8];
            *(bf16x8*)(Y + base + p * 8) = v;
        }
    }
}

// 768 blocks = 3/CU
__global__ __launch_bounds__(256, 3)
void gemm_qkv(const u16* __restrict__ xq, const u16* __restrict__ xk, const u16* __restrict__ xv,
              const u16* __restrict__ wq, const u16* __restrict__ wk, const u16* __restrict__ wv,
              u16* __restrict__ qb, u16* __restrict__ kb, u16* __restrict__ vt)
{
    if (blockIdx.z == 0)      gemm_body(xq, wq, qb, 0);
    else if (blockIdx.z == 1) gemm_body(xk, wk, kb, 0);
    else                      gemm_body(xv, wv, vt, 2);
}

// ---------------------------------------------------------------------------
// Output GEMM: 128x64 tiles -> 512 blocks (2/CU), GLL staging.
// Y fp32 [m][1024] + bias. Wave = 64x32 (4x2 MFMA tiles).
// ---------------------------------------------------------------------------
__global__ __launch_bounds__(256, 2)
void gemm_out64(const u16* __restrict__ X, const u16* __restrict__ W,
                float* __restrict__ Y, const float* __restrict__ bias)
{
    __shared__ u16 As[128 * 64];
    __shared__ u16 Bs[64 * 64];

    const int tid  = threadIdx.x;
    const int wave = tid >> 6;
    const int lane = tid & 63;
    const int lm   = lane & 15;
    const int quad = lane >> 4;
    const int m0 = blockIdx.x * 128;
    const int n0 = blockIdx.y * 64;
    const int wr = (wave & 1) * 64;
    const int wc = (wave >> 1) * 32;

    const int sr8 = lane >> 3, sc8 = (lane & 7) * 8;
    const u16* xg = X + (size_t)(m0 + wave * 32 + sr8) * 1024 + sc8;
    const u16* wg = W + (size_t)(n0 + wave * 16 + sr8) * 1024 + sc8;

    f32x4 acc[4][2] = {};

    for (int k0 = 0; k0 < 1024; k0 += 64) {
        __syncthreads();
        #pragma unroll
        for (int p = 0; p < 4; ++p)
            GLL16(xg + k0 + p * 8 * 1024, &As[(wave * 32 + p * 8) * 64]);
        #pragma unroll
        for (int p = 0; p < 2; ++p)
            GLL16(wg + k0 + p * 8 * 1024, &Bs[(wave * 16 + p * 8) * 64]);
        __syncthreads();
        #pragma unroll
        for (int kk = 0; kk < 64; kk += 32) {
            bf16x8 af[4], bf[2];
            #pragma unroll
            for (int t = 0; t < 4; ++t)
                af[t] = *(const bf16x8*)&As[(wr + t * 16 + lm) * 64 + kk + quad * 8];
            #pragma unroll
            for (int j = 0; j < 2; ++j)
                bf[j] = *(const bf16x8*)&Bs[(wc + j * 16 + lm) * 64 + kk + quad * 8];
            #pragma unroll
            for (int i = 0; i < 4; ++i)
                #pragma unroll
                for (int j = 0; j < 2; ++j)
                    acc[i][j] = __builtin_amdgcn_mfma_f32_16x16x32_bf16(af[i], bf[j], acc[i][j], 0, 0, 0);
        }
    }

    #pragma unroll
    for (int i = 0; i < 4; ++i)
        #pragma unroll
        for (int j = 0; j < 2; ++j) {
            const int C = n0 + wc + j * 16 + lm;
            const float bv = bias[C];
            #pragma unroll
            for (int r = 0; r < 4; ++r) {
                const int R = m0 + wr + i * 16 + quad * 4 + r;
                Y[(size_t)R * 1024 + C] = acc[i][j][r] + bv;
            }
        }
}

// ---------------------------------------------------------------------------
// Flash attention (R7-proven, best): bf16 MFMA, max-free softmax, key-chunk
// 128 with two-half P/PV through wave-private LDS, reg-prefetch K/V, XCD
// swizzle (all 16 q-blocks of one (n,h) share wid%8 -> one XCD's L2).
// Qb,Kb: [n,l,1024] bf16.  VT: [n,h,d,l] bf16.  O: [n,l,1024] bf16.
// ---------------------------------------------------------------------------
__global__ __launch_bounds__(256, 2)
void flash_attn_bf16(const u16* __restrict__ Qb, const u16* __restrict__ Kb,
                     const u16* __restrict__ VT, const int* __restrict__ mask,
                     u16* __restrict__ O)
{
    __shared__ u16 Ks[128 * 72];      // [key l][d]
    __shared__ u16 Vts[64 * 136];     // [d][key l]
    __shared__ u16 Ps[4][32 * 72];    // per-wave P [q][key-half]

    const int tid  = threadIdx.x;
    const int wave = tid >> 6;
    const int lane = tid & 63;
    const int lm   = lane & 15;
    const int quad = lane >> 4;

    // XCD-locality decode (perf-only; any mapping is correct)
    const int wid = blockIdx.x + 16 * blockIdx.y + 256 * blockIdx.z;  // 0..511
    const int idx = wid >> 3;
    const int hn  = (wid & 7) + 8 * (idx & 3);    // 0..31
    const int h   = hn & 15, n = hn >> 4;
    const int wq  = (idx >> 2) * 128 + wave * 32;

    const u16* Qh = Qb + ((size_t)n * SEQ) * 1024 + h * 64;
    const u16* Kh = Kb + ((size_t)n * SEQ) * 1024 + h * 64;
    const u16* Vh = VT + (((size_t)n * 16 + h) * 64) * SEQ;
    const int* mk = mask + (size_t)n * SEQ;
    u16* Pw = &Ps[wave][0];

    // Q fragments resident: A-layout m=lm, k=quad*8+j
    bf16x8 qf[2][2];
    #pragma unroll
    for (int t = 0; t < 2; ++t)
        #pragma unroll
        for (int s = 0; s < 2; ++s)
            qf[t][s] = *(const bf16x8*)(Qh + (size_t)(wq + t * 16 + lm) * 1024 + s * 32 + quad * 8);

    f32x4 o_acc[2][4] = {};
    float l_i[2][4] = {};

    // staging coords: K 128 rows x 64 d (2 thr/row); V 64 d x 128 keys (4 thr/row)
    const int kr = tid >> 1, kc = (tid & 1) * 32;
    const int vr = tid >> 2, vc = (tid & 3) * 32;

    bf16x8 ka[4], va[4];
    #pragma unroll
    for (int p = 0; p < 4; ++p) {
        ka[p] = *(const bf16x8*)(Kh + (size_t)kr * 1024 + kc + p * 8);
        va[p] = *(const bf16x8*)(Vh + (size_t)vr * SEQ + vc + p * 8);
    }

    const float cs = 0.125f * 1.44269504f;   // 1/sqrt(64) folded with log2(e)

    for (int c0 = 0; c0 < SEQ; c0 += 128) {
        __syncthreads();   // prior chunk's Ks/Vts reads complete
        #pragma unroll
        for (int p = 0; p < 4; ++p) {
            *(bf16x8*)&Ks[kr * 72 + kc + p * 8]   = ka[p];
            *(bf16x8*)&Vts[vr * 136 + vc + p * 8] = va[p];
        }
        __syncthreads();

        if (c0 + 128 < SEQ) {   // prefetch next chunk; in flight under compute
            #pragma unroll
            for (int p = 0; p < 4; ++p) {
                ka[p] = *(const bf16x8*)(Kh + (size_t)(c0 + 128 + kr) * 1024 + kc + p * 8);
                va[p] = *(const bf16x8*)(Vh + (size_t)vr * SEQ + c0 + 128 + vc + p * 8);
            }
        }

        // ---- S = Q K^T over 128 keys (8 n-tiles, 32 MFMAs)
        f32x4 s[2][8] = {};
        #pragma unroll
        for (int nt = 0; nt < 8; ++nt) {
            bf16x8 kf0 = *(const bf16x8*)&Ks[(nt * 16 + lm) * 72 + quad * 8];
            bf16x8 kf1 = *(const bf16x8*)&Ks[(nt * 16 + lm) * 72 + 32 + quad * 8];
            #pragma unroll
            for (int t = 0; t < 2; ++t) {
                s[t][nt] = __builtin_amdgcn_mfma_f32_16x16x32_bf16(qf[t][0], kf0, s[t][nt], 0, 0, 0);
                s[t][nt] = __builtin_amdgcn_mfma_f32_16x16x32_bf16(qf[t][1], kf1, s[t][nt], 0, 0, 0);
            }
        }

        // ---- exp2(scale*s), mask, row-sum accumulation (max-free)
        int msk[8];
        #pragma unroll
        for (int nt = 0; nt < 8; ++nt) msk[nt] = mk[c0 + nt * 16 + lm];
        #pragma unroll
        for (int t = 0; t < 2; ++t)
            #pragma unroll
            for (int nt = 0; nt < 8; ++nt)
                #pragma unroll
                for (int r = 0; r < 4; ++r) {
                    float e = EXP2F(s[t][nt][r] * cs);
                    e = msk[nt] ? e : 0.0f;
                    s[t][nt][r] = e;
                    l_i[t][r] += e;
                }

        // ---- two key-halves: P -> wave-private LDS, then PV (no barriers)
        #pragma unroll
        for (int half = 0; half < 2; ++half) {
            #pragma unroll
            for (int t = 0; t < 2; ++t)
                #pragma unroll
                for (int ntl = 0; ntl < 4; ++ntl)
                    #pragma unroll
                    for (int r = 0; r < 4; ++r)
                        Pw[(t * 16 + quad * 4 + r) * 72 + ntl * 16 + lm] =
                            f2bf(s[t][half * 4 + ntl][r]);

            #pragma unroll
            for (int ksl = 0; ksl < 2; ++ksl) {
                bf16x8 pf[2];
                #pragma unroll
                for (int t = 0; t < 2; ++t)
                    pf[t] = *(const bf16x8*)&Pw[(t * 16 + lm) * 72 + ksl * 32 + quad * 8];
                #pragma unroll
                for (int dt = 0; dt < 4; ++dt) {
                    bf16x8 vf = *(const bf16x8*)&Vts[(dt * 16 + lm) * 136 + half * 64 + ksl * 32 + quad * 8];
                    #pragma unroll
                    for (int t = 0; t < 2; ++t)
                        o_acc[t][dt] = __builtin_amdgcn_mfma_f32_16x16x32_bf16(pf[t], vf, o_acc[t][dt], 0, 0, 0);
                }
            }
        }
    }

    // ---- epilogue: one l reduction, normalize, store
    #pragma unroll
    for (int t = 0; t < 2; ++t)
        #pragma unroll
        for (int r = 0; r < 4; ++r) {
            float v = l_i[t][r];
            #pragma unroll
            for (int off = 1; off < 16; off <<= 1) v += __shfl_xor(v, off);
            l_i[t][r] = 1.0f / v;
        }
    #pragma unroll
    for (int t = 0; t < 2; ++t)
        #pragma unroll
        for (int dt = 0; dt < 4; ++dt)
            #pragma unroll
            for (int r = 0; r < 4; ++r) {
                const int ql = wq + t * 16 + quad * 4 + r;
                const int col = h * 64 + dt * 16 + lm;
                O[((size_t)n * SEQ + ql) * 1024 + col] = f2bf(o_acc[t][dt][r] * l_i[t][r]);
            }
}

// ---------------------------------------------------------------------------
extern "C" void kernel_launch(void* const* d_in, const int* in_sizes, int n_in,
                              void* d_out, int out_size, void* d_ws, size_t ws_size,
                              hipStream_t stream)
{
    const float* values = (const float*)d_in[0];
    const float* keys   = (const float*)d_in[1];
    const float* query  = (const float*)d_in[2];
    const int*   mask   = (const int*)d_in[3];
    const float* W_q    = (const float*)d_in[4];
    const float* W_k    = (const float*)d_in[5];
    const float* W_v    = (const float*)d_in[6];
    const float* W_o    = (const float*)d_in[7];
    const float* b_o    = (const float*)d_in[8];

    const size_t NTOK = (size_t)NBATCH * SEQ * 1024;  // 4194304
    const size_t WSZ  = 1024 * 1024;
    u16* p = (u16*)d_ws;
    u16* qb    = p; p += NTOK;   // q  [n,l,e] bf16
    u16* kb    = p; p += NTOK;   // k  [n,l,e] bf16
    u16* vt    = p; p += NTOK;   // v^T[n,h,d,l] bf16
    u16* xq    = p; p += NTOK;   // bf16 input casts
    u16* xk    = p; p += NTOK;
    u16* xv    = p; p += NTOK;
    u16* attnb = p; p += NTOK;   // attn out [n,l,e] bf16
    u16* wqb   = p; p += WSZ;    // bf16 weight casts
    u16* wkb   = p; p += WSZ;
    u16* wvb   = p; p += WSZ;
    u16* wob   = p; p += WSZ;

    cast_all<<<dim3(4096, 4), 256, 0, stream>>>(query, keys, values,
                                                W_q, W_k, W_v, W_o,
                                                xq, xk, xv, wqb, wkb, wvb, wob);

    gemm_qkv<<<dim3(32, 8, 3), 256, 0, stream>>>(xq, xk, xv, wqb, wkb, wvb, qb, kb, vt);

    flash_attn_bf16<<<dim3(16, 16, 2), 256, 0, stream>>>(qb, kb, vt, mask, attnb);

    gemm_out64<<<dim3(32, 16), 256, 0, stream>>>(attnb, wob, (float*)d_out, b_o);
}